// Round 4
// baseline (295.938 us; speedup 1.0000x reference)
//
#include <hip/hip_runtime.h>
#include <hip/hip_cooperative_groups.h>
#include <math.h>

namespace cg = cooperative_groups;

#define TWO_PI_F 6.28318530717958647692f
#define BN_EPS_F 1e-5f
#define NBC 512   // cooperative grid blocks
#define NT 256

// ---------------------------------------------------------------------------
// Workspace layout (float offsets on d_ws):
//   [STAT_OFF + 32*j] j=0..7 : BN stats (sum0..3, sumsq0..3), 128-B padded
//   [BMIN_OFF..+512)         : per-block min      (coop path)
//   [BMAX_OFF..+512)         : per-block max      (coop path)
//   [TAB_OFF..+576)          : UrT[16][16] | UiT[16][16] | AT[16][4]
//   [MINK_OFF],[MAXK_OFF]    : unsigned min/max keys (fallback path)
// ---------------------------------------------------------------------------
#define STAT_OFF 0
#define STAT_STRIDE 32
#define BMIN_OFF 256
#define BMAX_OFF 768
#define TAB_OFF 1280
#define MINK_OFF 1856
#define MAXK_OFF 1888

__device__ __forceinline__ unsigned f2key(float f) {
  unsigned u = __float_as_uint(f);
  return (u & 0x80000000u) ? ~u : (u | 0x80000000u);
}
__device__ __forceinline__ float key2f(unsigned k) {
  unsigned u = (k & 0x80000000u) ? (k ^ 0x80000000u) : ~k;
  return __uint_as_float(u);
}

// Build the fixed tables: circuit unitary UrT/UiT ([a][k], transposed) and
// AT = Zparity^T fc_w^T ([k][j]); zero BN stats; optionally init min/max keys.
__device__ void build_tables(int tid, const float* __restrict__ w,
                             const float* __restrict__ fc_w, float* wsf,
                             bool init_keys) {
  if (tid < 16) {
    float sr[16], si[16];
#pragma unroll
    for (int k = 0; k < 16; ++k) { sr[k] = (k == tid) ? 1.f : 0.f; si[k] = 0.f; }
#pragma unroll
    for (int l = 0; l < 3; ++l) {
#pragma unroll
      for (int i = 0; i < 4; ++i) {
        const int m = 8 >> i;
        float ryc, rys, rzc, rzs;
        __sincosf(0.5f * w[(l * 4 + i) * 2 + 0], &rys, &ryc);
        __sincosf(0.5f * w[(l * 4 + i) * 2 + 1], &rzs, &rzc);
#pragma unroll
        for (int k = 0; k < 16; ++k) {
          if (!(k & m)) {
            int k1 = k | m;
            float a0r = sr[k], a0i = si[k], a1r = sr[k1], a1i = si[k1];
            sr[k] = ryc * a0r - rys * a1r;
            si[k] = ryc * a0i - rys * a1i;
            sr[k1] = rys * a0r + ryc * a1r;
            si[k1] = rys * a0i + ryc * a1i;
          }
        }
#pragma unroll
        for (int k = 0; k < 16; ++k) {
          float ps = (k & m) ? rzs : -rzs;
          float r = sr[k], ii = si[k];
          sr[k] = r * rzc - ii * ps;
          si[k] = r * ps + ii * rzc;
        }
      }
#pragma unroll
      for (int c = 0; c < 4; ++c) {
        const int mc = 8 >> c;
        const int mt = 8 >> ((c + 1) & 3);
#pragma unroll
        for (int k = 0; k < 16; ++k) {
          if ((k & mc) && !(k & mt)) {
            int k2 = k | mt;
            float tt;
            tt = sr[k]; sr[k] = sr[k2]; sr[k2] = tt;
            tt = si[k]; si[k] = si[k2]; si[k2] = tt;
          }
        }
      }
    }
#pragma unroll
    for (int k = 0; k < 16; ++k) {
      wsf[TAB_OFF + tid * 16 + k] = sr[k];
      wsf[TAB_OFF + 256 + tid * 16 + k] = si[k];
    }
  } else if (tid == 16) {
    for (int k = 0; k < 16; ++k)
      for (int j = 0; j < 4; ++j) {
        float s = 0.f;
        for (int i = 0; i < 4; ++i)
          s += fc_w[j * 4 + i] * ((k & (8 >> i)) ? -1.f : 1.f);
        wsf[TAB_OFF + 512 + k * 4 + j] = s;
      }
  } else if (tid == 17 && init_keys) {
    unsigned* wsu = (unsigned*)wsf;
    wsu[MINK_OFF] = 0xFFFFFFFFu;
    wsu[MAXK_OFF] = 0x00000000u;
  } else if (tid >= 24 && tid < 32) {
    wsf[STAT_OFF + (tid - 24) * STAT_STRIDE] = 0.0f;
  }
}

// Compute o[4] (pre-BN, no bias) for one sample given half-angle sin/cos.
// tab points at TAB_OFF (const restrict -> scalar loads).
template <int PAIR>
__device__ __forceinline__ void qfc_pair(const float* __restrict__ tab,
                                         const float* c0, const float* s0,
                                         const float* c1, const float* s1,
                                         float* o0, float* o1) {
  const float* __restrict__ Ur = tab;
  const float* __restrict__ Ui = tab + 256;
  const float* __restrict__ At = tab + 512;
  float A01_0[4] = {c0[0] * c0[1], c0[0] * s0[1], s0[0] * c0[1], s0[0] * s0[1]};
  float A23_0[4] = {c0[2] * c0[3], c0[2] * s0[3], s0[2] * c0[3], s0[2] * s0[3]};
  float A01_1[4] = {c1[0] * c1[1], c1[0] * s1[1], s1[0] * c1[1], s1[0] * s1[1]};
  float A23_1[4] = {c1[2] * c1[3], c1[2] * s1[3], s1[2] * c1[3], s1[2] * s1[3]};
  float yr0[16], yi0[16], yr1[16], yi1[16];
#pragma unroll
  for (int k = 0; k < 16; ++k) { yr0[k] = yi0[k] = yr1[k] = yi1[k] = 0.f; }
#pragma unroll
  for (int a = 0; a < 16; ++a) {
    float va0 = A01_0[a >> 2] * A23_0[a & 3];
    float va1 = A01_1[a >> 2] * A23_1[a & 3];
#pragma unroll
    for (int k = 0; k < 16; ++k) {
      float ur = Ur[a * 16 + k], ui = Ui[a * 16 + k];
      yr0[k] = fmaf(ur, va0, yr0[k]);
      yi0[k] = fmaf(ui, va0, yi0[k]);
      yr1[k] = fmaf(ur, va1, yr1[k]);
      yi1[k] = fmaf(ui, va1, yi1[k]);
    }
  }
#pragma unroll
  for (int j = 0; j < 4; ++j) { o0[j] = 0.f; o1[j] = 0.f; }
#pragma unroll
  for (int k = 0; k < 16; ++k) {
    float p0 = fmaf(yr0[k], yr0[k], yi0[k] * yi0[k]);
    float p1 = fmaf(yr1[k], yr1[k], yi1[k] * yi1[k]);
#pragma unroll
    for (int j = 0; j < 4; ++j) {
      float av = At[k * 4 + j];
      o0[j] = fmaf(av, p0, o0[j]);
      o1[j] = fmaf(av, p1, o1[j]);
    }
  }
}

// ===========================================================================
// Cooperative fused kernel: 512 blocks x 256 threads, 4 samples/thread.
// ===========================================================================
__global__ __launch_bounds__(NT, 2) void k_fused(
    const float* __restrict__ x, const float* __restrict__ w,
    const float* __restrict__ fc_w, const float* __restrict__ gamma,
    const float* __restrict__ beta, float* wsf,
    const float* __restrict__ tab, float* __restrict__ out, int B) {
  cg::grid_group grid = cg::this_grid();
  const int tid = threadIdx.x;
  const int gtid = blockIdx.x * NT + tid;
  const int H = NBC * NT;  // 131072
  const int wv = tid >> 6, ln = tid & 63;
  __shared__ float sred[4][8];

  // ----- Phase 1: load 4 rows, block min/max; block 0 builds tables -----
  float4 xs[4];
  bool hp[4];
#pragma unroll
  for (int p = 0; p < 4; ++p) {
    int s = gtid + p * H;
    hp[p] = s < B;
    xs[p] = hp[p] ? *(const float4*)(x + (size_t)s * 16) : make_float4(0, 0, 0, 0);
  }
  float fmn = __builtin_inff(), fmx = -__builtin_inff();
#pragma unroll
  for (int p = 0; p < 4; ++p) {
    if (hp[p]) {
      fmn = fminf(fmn, fminf(fminf(xs[p].x, xs[p].y), fminf(xs[p].z, xs[p].w)));
      fmx = fmaxf(fmx, fmaxf(fmaxf(xs[p].x, xs[p].y), fmaxf(xs[p].z, xs[p].w)));
    }
  }
#pragma unroll
  for (int d = 32; d; d >>= 1) {
    fmn = fminf(fmn, __shfl_down(fmn, d));
    fmx = fmaxf(fmx, __shfl_down(fmx, d));
  }
  if (ln == 0) { sred[wv][0] = fmn; sred[wv][1] = fmx; }
  __syncthreads();
  if (tid == 0) {
    wsf[BMIN_OFF + blockIdx.x] =
        fminf(fminf(sred[0][0], sred[1][0]), fminf(sred[2][0], sred[3][0]));
    wsf[BMAX_OFF + blockIdx.x] =
        fmaxf(fmaxf(sred[0][1], sred[1][1]), fmaxf(sred[2][1], sred[3][1]));
  }
  if (blockIdx.x == 0) build_tables(tid, w, fc_w, wsf, false);

  __threadfence();
  grid.sync();

  // ----- Phase 2: global min/max; compute 4 samples; BN stats -----
  float gm = __builtin_inff(), gM = -__builtin_inff();
#pragma unroll
  for (int q = 0; q < NBC / 64; ++q) {
    int i = ln + q * 64;
    gm = fminf(gm, wsf[BMIN_OFF + i]);
    gM = fmaxf(gM, wsf[BMAX_OFF + i]);
  }
#pragma unroll
  for (int d = 32; d; d >>= 1) {
    gm = fminf(gm, __shfl_down(gm, d));
    gM = fmaxf(gM, __shfl_down(gM, d));
  }
  gm = __shfl(gm, 0);
  gM = __shfl(gM, 0);
  const float ssc = TWO_PI_F * 0.5f / (gM - gm + 1e-8f);  // half-angle scale

  float o[4][4];
#pragma unroll
  for (int pp = 0; pp < 2; ++pp) {
    const float4 xa = xs[pp * 2], xb = xs[pp * 2 + 1];
    float a0[4] = {xa.x, xa.y, xa.z, xa.w};
    float a1[4] = {xb.x, xb.y, xb.z, xb.w};
    float c0[4], s0[4], c1[4], s1[4];
#pragma unroll
    for (int i = 0; i < 4; ++i) {
      __sincosf((a0[i] - gm) * ssc, &s0[i], &c0[i]);
      __sincosf((a1[i] - gm) * ssc, &s1[i], &c1[i]);
    }
    qfc_pair<0>(tab, c0, s0, c1, s1, o[pp * 2], o[pp * 2 + 1]);
  }

  float vals[8];
#pragma unroll
  for (int j = 0; j < 4; ++j) {
    float s = 0.f, ss = 0.f;
#pragma unroll
    for (int p = 0; p < 4; ++p) {
      float v = hp[p] ? o[p][j] : 0.f;
      s += v;
      ss = fmaf(v, v, ss);
    }
    vals[j] = s;
    vals[4 + j] = ss;
  }
#pragma unroll
  for (int j = 0; j < 8; ++j) {
#pragma unroll
    for (int d = 32; d; d >>= 1) vals[j] += __shfl_down(vals[j], d);
  }
  __syncthreads();
  if (ln == 0) {
#pragma unroll
    for (int j = 0; j < 8; ++j) sred[wv][j] = vals[j];
  }
  __syncthreads();
  if (tid < 8) {
    float s = sred[0][tid] + sred[1][tid] + sred[2][tid] + sred[3][tid];
    atomicAdd(wsf + STAT_OFF + tid * STAT_STRIDE, s);
  }

  __threadfence();
  grid.sync();

  // ----- Phase 3: BN finalize from registers -----
  const float inv = 1.0f / (float)B;
  float sc[4], sh[4];
#pragma unroll
  for (int j = 0; j < 4; ++j) {
    float mean = wsf[STAT_OFF + j * STAT_STRIDE] * inv;
    float var = wsf[STAT_OFF + (4 + j) * STAT_STRIDE] * inv - mean * mean;
    float is = rsqrtf(var + BN_EPS_F);
    sc[j] = gamma[j] * is;
    sh[j] = beta[j] - mean * sc[j];
  }
#pragma unroll
  for (int p = 0; p < 4; ++p) {
    if (hp[p]) {
      int s = gtid + p * H;
      *(float4*)(out + (size_t)s * 4) =
          make_float4(fmaf(o[p][0], sc[0], sh[0]), fmaf(o[p][1], sc[1], sh[1]),
                      fmaf(o[p][2], sc[2], sh[2]), fmaf(o[p][3], sc[3], sh[3]));
    }
  }
}

// ===========================================================================
// Fallback path (verified R2 structure): 4 plain kernels.
// ===========================================================================
__global__ void k_init_fb(const float* __restrict__ w,
                          const float* __restrict__ fc_w, float* wsf) {
  build_tables(threadIdx.x, w, fc_w, wsf, true);
}

__global__ __launch_bounds__(256) void k_minmax_fb(const float* __restrict__ x,
                                                   unsigned* __restrict__ wsu,
                                                   int B) {
  float fmn = __builtin_inff(), fmx = -__builtin_inff();
  for (int r = blockIdx.x * blockDim.x + threadIdx.x; r < B;
       r += gridDim.x * blockDim.x) {
    float4 v = *(const float4*)(x + (size_t)r * 16);
    fmn = fminf(fmn, fminf(fminf(v.x, v.y), fminf(v.z, v.w)));
    fmx = fmaxf(fmx, fmaxf(fmaxf(v.x, v.y), fmaxf(v.z, v.w)));
  }
#pragma unroll
  for (int d = 32; d; d >>= 1) {
    fmn = fminf(fmn, __shfl_down(fmn, d));
    fmx = fmaxf(fmx, __shfl_down(fmx, d));
  }
  __shared__ float smn[4], smx[4];
  int wv = threadIdx.x >> 6, ln = threadIdx.x & 63;
  if (ln == 0) { smn[wv] = fmn; smx[wv] = fmx; }
  __syncthreads();
  if (threadIdx.x == 0) {
    atomicMin(&wsu[MINK_OFF],
              f2key(fminf(fminf(smn[0], smn[1]), fminf(smn[2], smn[3]))));
    atomicMax(&wsu[MAXK_OFF],
              f2key(fmaxf(fmaxf(smx[0], smx[1]), fmaxf(smx[2], smx[3]))));
  }
}

__global__ __launch_bounds__(256) void k_main_fb(const float* __restrict__ x,
                                                 float* wsf,
                                                 const float* __restrict__ tab,
                                                 float* __restrict__ out, int B) {
  int b = blockIdx.x * 256 + threadIdx.x;
  const unsigned* wsu = (const unsigned*)wsf;
  float mn = key2f(wsu[MINK_OFF]);
  float mx = key2f(wsu[MAXK_OFF]);
  const float ssc = TWO_PI_F * 0.5f / (mx - mn + 1e-8f);
  float o0[4] = {0, 0, 0, 0}, o1[4];
  if (b < B) {
    float4 xv = *(const float4*)(x + (size_t)b * 16);
    float a0[4] = {xv.x, xv.y, xv.z, xv.w};
    float c0[4], s0[4];
#pragma unroll
    for (int i = 0; i < 4; ++i) __sincosf((a0[i] - mn) * ssc, &s0[i], &c0[i]);
    qfc_pair<1>(tab, c0, s0, c0, s0, o0, o1);
    *(float4*)(out + (size_t)b * 4) = make_float4(o0[0], o0[1], o0[2], o0[3]);
  }
  float vals[8] = {o0[0], o0[1], o0[2], o0[3],
                   o0[0] * o0[0], o0[1] * o0[1], o0[2] * o0[2], o0[3] * o0[3]};
#pragma unroll
  for (int j = 0; j < 8; ++j) {
#pragma unroll
    for (int d = 32; d; d >>= 1) vals[j] += __shfl_down(vals[j], d);
  }
  __shared__ float red[4][8];
  int wv = threadIdx.x >> 6, ln = threadIdx.x & 63;
  if (ln == 0) {
#pragma unroll
    for (int j = 0; j < 8; ++j) red[wv][j] = vals[j];
  }
  __syncthreads();
  if (threadIdx.x < 8) {
    float s = red[0][threadIdx.x] + red[1][threadIdx.x] + red[2][threadIdx.x] +
              red[3][threadIdx.x];
    atomicAdd(wsf + STAT_OFF + threadIdx.x * STAT_STRIDE, s);
  }
}

__global__ __launch_bounds__(256) void k_final_fb(float* __restrict__ out,
                                                  const float* __restrict__ wsf,
                                                  const float* __restrict__ gamma,
                                                  const float* __restrict__ beta,
                                                  int B) {
  int b = blockIdx.x * 256 + threadIdx.x;
  if (b >= B) return;
  float inv = 1.0f / (float)B;
  float4 v = *(float4*)(out + (size_t)b * 4);
  float vv[4] = {v.x, v.y, v.z, v.w};
  float res[4];
#pragma unroll
  for (int j = 0; j < 4; ++j) {
    float mean = wsf[STAT_OFF + j * STAT_STRIDE] * inv;
    float var = wsf[STAT_OFF + (4 + j) * STAT_STRIDE] * inv - mean * mean;
    res[j] = gamma[j] * (vv[j] - mean) * rsqrtf(var + BN_EPS_F) + beta[j];
  }
  *(float4*)(out + (size_t)b * 4) = make_float4(res[0], res[1], res[2], res[3]);
}

extern "C" void kernel_launch(void* const* d_in, const int* in_sizes, int n_in,
                              void* d_out, int out_size, void* d_ws, size_t ws_size,
                              hipStream_t stream) {
  const float* x = (const float*)d_in[0];
  const float* w = (const float*)d_in[1];
  const float* fc_w = (const float*)d_in[2];
  const float* gamma = (const float*)d_in[4];
  const float* beta = (const float*)d_in[5];
  float* out = (float*)d_out;
  float* wsf = (float*)d_ws;
  const float* tab = wsf + TAB_OFF;
  int B = in_sizes[0] / 16;

  void* args[] = {(void*)&x,    (void*)&w,   (void*)&fc_w,
                  (void*)&gamma, (void*)&beta, (void*)&wsf,
                  (void*)&tab,  (void*)&out, (void*)&B};
  hipError_t e = hipLaunchCooperativeKernel((void*)k_fused, dim3(NBC), dim3(NT),
                                            args, 0, stream);
  if (e != hipSuccess) {
    // Fallback: verified 4-kernel structure.
    k_init_fb<<<1, 64, 0, stream>>>(w, fc_w, wsf);
    k_minmax_fb<<<1024, 256, 0, stream>>>(x, (unsigned*)d_ws, B);
    k_main_fb<<<(B + 255) / 256, 256, 0, stream>>>(x, wsf, tab, out, B);
    k_final_fb<<<(B + 255) / 256, 256, 0, stream>>>(out, wsf, gamma, beta, B);
  }
}

// Round 5
// 220.021 us; speedup vs baseline: 1.3450x; 1.3450x over previous
//
#include <hip/hip_runtime.h>
#include <math.h>

#define TWO_PI_F 6.28318530717958647692f
#define BN_EPS_F 1e-5f
#define NBC 512   // cooperative grid blocks
#define NT 256

// ---------------------------------------------------------------------------
// Workspace layout (float offsets on d_ws):
//   [STAT_OFF + 32*j] j=0..7 : BN stats (sum0..3, sumsq0..3), 128-B padded
//   [BMIN_OFF..+512)         : per-block min
//   [BMAX_OFF..+512)         : per-block max
//   [TAB_OFF..+576)          : UrT[16][16] | UiT[16][16] | AT[16][4]
//   [MINK_OFF],[MAXK_OFF]    : unsigned min/max keys (fallback path)
//   [CNT_OFF + b*256 + q*32] : barrier b sub-counter q (128-B padded), b=0,1 q=0..7
// ---------------------------------------------------------------------------
#define STAT_OFF 0
#define STAT_STRIDE 32
#define BMIN_OFF 256
#define BMAX_OFF 768
#define TAB_OFF 1280
#define MINK_OFF 1856
#define MAXK_OFF 1888
#define CNT_OFF 1920

__device__ __forceinline__ unsigned f2key(float f) {
  unsigned u = __float_as_uint(f);
  return (u & 0x80000000u) ? ~u : (u | 0x80000000u);
}
__device__ __forceinline__ float key2f(unsigned k) {
  unsigned u = (k & 0x80000000u) ? (k ^ 0x80000000u) : ~k;
  return __uint_as_float(u);
}

// Fast grid barrier: 8 line-padded sub-counters, agent-scope atomics, s_sleep poll.
__device__ __forceinline__ void gbarrier(unsigned* cnt, int idx, int target) {
  __syncthreads();
  if (threadIdx.x == 0) {
    unsigned* mine = cnt + idx * 256 + (blockIdx.x & 7) * 32;
    __hip_atomic_fetch_add(mine, 1u, __ATOMIC_RELEASE, __HIP_MEMORY_SCOPE_AGENT);
    for (;;) {
      unsigned s = 0;
#pragma unroll
      for (int q = 0; q < 8; ++q)
        s += __hip_atomic_load(cnt + idx * 256 + q * 32, __ATOMIC_RELAXED,
                               __HIP_MEMORY_SCOPE_AGENT);
      if (s >= (unsigned)target) break;
      __builtin_amdgcn_s_sleep(1);
    }
  }
  __syncthreads();
  __threadfence();
}

// Build fixed tables: UrT/UiT ([a][k]) and AT=Zparity^T fc_w^T ([k][j]);
// zero BN stats, barrier counters, and fallback min/max keys.
__global__ void k_init(const float* __restrict__ w,
                       const float* __restrict__ fc_w, float* wsf) {
  int tid = threadIdx.x;
  if (tid < 16) {
    float sr[16], si[16];
#pragma unroll
    for (int k = 0; k < 16; ++k) { sr[k] = (k == tid) ? 1.f : 0.f; si[k] = 0.f; }
#pragma unroll
    for (int l = 0; l < 3; ++l) {
#pragma unroll
      for (int i = 0; i < 4; ++i) {
        const int m = 8 >> i;
        float ryc, rys, rzc, rzs;
        __sincosf(0.5f * w[(l * 4 + i) * 2 + 0], &rys, &ryc);
        __sincosf(0.5f * w[(l * 4 + i) * 2 + 1], &rzs, &rzc);
#pragma unroll
        for (int k = 0; k < 16; ++k) {
          if (!(k & m)) {
            int k1 = k | m;
            float a0r = sr[k], a0i = si[k], a1r = sr[k1], a1i = si[k1];
            sr[k] = ryc * a0r - rys * a1r;
            si[k] = ryc * a0i - rys * a1i;
            sr[k1] = rys * a0r + ryc * a1r;
            si[k1] = rys * a0i + ryc * a1i;
          }
        }
#pragma unroll
        for (int k = 0; k < 16; ++k) {
          float ps = (k & m) ? rzs : -rzs;
          float r = sr[k], ii = si[k];
          sr[k] = r * rzc - ii * ps;
          si[k] = r * ps + ii * rzc;
        }
      }
#pragma unroll
      for (int c = 0; c < 4; ++c) {
        const int mc = 8 >> c;
        const int mt = 8 >> ((c + 1) & 3);
#pragma unroll
        for (int k = 0; k < 16; ++k) {
          if ((k & mc) && !(k & mt)) {
            int k2 = k | mt;
            float tt;
            tt = sr[k]; sr[k] = sr[k2]; sr[k2] = tt;
            tt = si[k]; si[k] = si[k2]; si[k2] = tt;
          }
        }
      }
    }
#pragma unroll
    for (int k = 0; k < 16; ++k) {
      wsf[TAB_OFF + tid * 16 + k] = sr[k];
      wsf[TAB_OFF + 256 + tid * 16 + k] = si[k];
    }
  } else if (tid == 16) {
    for (int k = 0; k < 16; ++k)
      for (int j = 0; j < 4; ++j) {
        float s = 0.f;
        for (int i = 0; i < 4; ++i)
          s += fc_w[j * 4 + i] * ((k & (8 >> i)) ? -1.f : 1.f);
        wsf[TAB_OFF + 512 + k * 4 + j] = s;
      }
  } else if (tid == 17) {
    unsigned* wsu = (unsigned*)wsf;
    wsu[MINK_OFF] = 0xFFFFFFFFu;
    wsu[MAXK_OFF] = 0x00000000u;
  } else if (tid >= 24 && tid < 32) {
    wsf[STAT_OFF + (tid - 24) * STAT_STRIDE] = 0.0f;
  } else if (tid >= 32 && tid < 48) {
    int t = tid - 32;
    ((unsigned*)wsf)[CNT_OFF + ((t >> 3) & 1) * 256 + (t & 7) * 32] = 0u;
  }
}

// Two-sample fused circuit+linear: o = A|U v|^2 (no bias; constant bias
// cancels exactly in BatchNorm). tab -> scalar loads (wave-uniform).
__device__ __forceinline__ void qfc_pair(const float* __restrict__ tab,
                                         const float* c0, const float* s0,
                                         const float* c1, const float* s1,
                                         float* o0, float* o1) {
  const float* __restrict__ Ur = tab;
  const float* __restrict__ Ui = tab + 256;
  const float* __restrict__ At = tab + 512;
  float A01_0[4] = {c0[0] * c0[1], c0[0] * s0[1], s0[0] * c0[1], s0[0] * s0[1]};
  float A23_0[4] = {c0[2] * c0[3], c0[2] * s0[3], s0[2] * c0[3], s0[2] * s0[3]};
  float A01_1[4] = {c1[0] * c1[1], c1[0] * s1[1], s1[0] * c1[1], s1[0] * s1[1]};
  float A23_1[4] = {c1[2] * c1[3], c1[2] * s1[3], s1[2] * c1[3], s1[2] * s1[3]};
  float yr0[16], yi0[16], yr1[16], yi1[16];
#pragma unroll
  for (int k = 0; k < 16; ++k) { yr0[k] = yi0[k] = yr1[k] = yi1[k] = 0.f; }
#pragma unroll
  for (int a = 0; a < 16; ++a) {
    float va0 = A01_0[a >> 2] * A23_0[a & 3];
    float va1 = A01_1[a >> 2] * A23_1[a & 3];
#pragma unroll
    for (int k = 0; k < 16; ++k) {
      float ur = Ur[a * 16 + k], ui = Ui[a * 16 + k];
      yr0[k] = fmaf(ur, va0, yr0[k]);
      yi0[k] = fmaf(ui, va0, yi0[k]);
      yr1[k] = fmaf(ur, va1, yr1[k]);
      yi1[k] = fmaf(ui, va1, yi1[k]);
    }
  }
#pragma unroll
  for (int j = 0; j < 4; ++j) { o0[j] = 0.f; o1[j] = 0.f; }
#pragma unroll
  for (int k = 0; k < 16; ++k) {
    float p0 = fmaf(yr0[k], yr0[k], yi0[k] * yi0[k]);
    float p1 = fmaf(yr1[k], yr1[k], yi1[k] * yi1[k]);
#pragma unroll
    for (int j = 0; j < 4; ++j) {
      float av = At[k * 4 + j];
      o0[j] = fmaf(av, p0, o0[j]);
      o1[j] = fmaf(av, p1, o1[j]);
    }
  }
}

// ===========================================================================
// Cooperative-launched fused kernel with hand-rolled grid barriers.
// 512 blocks x 256 threads, 4 samples/thread.
// ===========================================================================
__global__ __launch_bounds__(NT, 2) void k_fused(
    const float* __restrict__ x, const float* __restrict__ gamma,
    const float* __restrict__ beta, float* wsf, const float* __restrict__ tab,
    float* __restrict__ out, int B) {
  const int tid = threadIdx.x;
  const int gtid = blockIdx.x * NT + tid;
  const int H = NBC * NT;  // 131072
  const int wv = tid >> 6, ln = tid & 63;
  unsigned* cnt = (unsigned*)wsf;
  __shared__ float sred[4][8];

  // ----- Phase 1: load 4 rows, block min/max -> per-block slots -----
  float4 xs[4];
  bool hp[4];
#pragma unroll
  for (int p = 0; p < 4; ++p) {
    int s = gtid + p * H;
    hp[p] = s < B;
    xs[p] = hp[p] ? *(const float4*)(x + (size_t)s * 16) : make_float4(0, 0, 0, 0);
  }
  float fmn = __builtin_inff(), fmx = -__builtin_inff();
#pragma unroll
  for (int p = 0; p < 4; ++p) {
    if (hp[p]) {
      fmn = fminf(fmn, fminf(fminf(xs[p].x, xs[p].y), fminf(xs[p].z, xs[p].w)));
      fmx = fmaxf(fmx, fmaxf(fmaxf(xs[p].x, xs[p].y), fmaxf(xs[p].z, xs[p].w)));
    }
  }
#pragma unroll
  for (int d = 32; d; d >>= 1) {
    fmn = fminf(fmn, __shfl_down(fmn, d));
    fmx = fmaxf(fmx, __shfl_down(fmx, d));
  }
  if (ln == 0) { sred[wv][0] = fmn; sred[wv][1] = fmx; }
  __syncthreads();
  if (tid == 0) {
    float bm = fminf(fminf(sred[0][0], sred[1][0]), fminf(sred[2][0], sred[3][0]));
    float bM = fmaxf(fmaxf(sred[0][1], sred[1][1]), fmaxf(sred[2][1], sred[3][1]));
    __hip_atomic_store(&wsf[BMIN_OFF + blockIdx.x], bm, __ATOMIC_RELEASE,
                       __HIP_MEMORY_SCOPE_AGENT);
    __hip_atomic_store(&wsf[BMAX_OFF + blockIdx.x], bM, __ATOMIC_RELEASE,
                       __HIP_MEMORY_SCOPE_AGENT);
  }

  gbarrier(cnt + CNT_OFF, 0, NBC);

  // ----- Phase 2: global min/max from slots (per-wave), compute, BN stats -----
  float gm = __builtin_inff(), gM = -__builtin_inff();
#pragma unroll
  for (int q = 0; q < NBC / 64; ++q) {
    int i = ln + q * 64;
    gm = fminf(gm, __hip_atomic_load(&wsf[BMIN_OFF + i], __ATOMIC_RELAXED,
                                     __HIP_MEMORY_SCOPE_AGENT));
    gM = fmaxf(gM, __hip_atomic_load(&wsf[BMAX_OFF + i], __ATOMIC_RELAXED,
                                     __HIP_MEMORY_SCOPE_AGENT));
  }
#pragma unroll
  for (int d = 32; d; d >>= 1) {
    gm = fminf(gm, __shfl_down(gm, d));
    gM = fmaxf(gM, __shfl_down(gM, d));
  }
  gm = __shfl(gm, 0);
  gM = __shfl(gM, 0);
  const float ssc = TWO_PI_F * 0.5f / (gM - gm + 1e-8f);  // half-angle scale

  float o[4][4];
#pragma unroll
  for (int pp = 0; pp < 2; ++pp) {
    const float4 xa = xs[pp * 2], xb = xs[pp * 2 + 1];
    float a0[4] = {xa.x, xa.y, xa.z, xa.w};
    float a1[4] = {xb.x, xb.y, xb.z, xb.w};
    float c0[4], s0[4], c1[4], s1[4];
#pragma unroll
    for (int i = 0; i < 4; ++i) {
      __sincosf((a0[i] - gm) * ssc, &s0[i], &c0[i]);
      __sincosf((a1[i] - gm) * ssc, &s1[i], &c1[i]);
    }
    qfc_pair(tab, c0, s0, c1, s1, o[pp * 2], o[pp * 2 + 1]);
  }

  float vals[8];
#pragma unroll
  for (int j = 0; j < 4; ++j) {
    float s = 0.f, ss = 0.f;
#pragma unroll
    for (int p = 0; p < 4; ++p) {
      float v = hp[p] ? o[p][j] : 0.f;
      s += v;
      ss = fmaf(v, v, ss);
    }
    vals[j] = s;
    vals[4 + j] = ss;
  }
#pragma unroll
  for (int j = 0; j < 8; ++j) {
#pragma unroll
    for (int d = 32; d; d >>= 1) vals[j] += __shfl_down(vals[j], d);
  }
  __syncthreads();
  if (ln == 0) {
#pragma unroll
    for (int j = 0; j < 8; ++j) sred[wv][j] = vals[j];
  }
  __syncthreads();
  if (tid < 8) {
    float s = sred[0][tid] + sred[1][tid] + sred[2][tid] + sred[3][tid];
    atomicAdd(wsf + STAT_OFF + tid * STAT_STRIDE, s);  // device-scope (m20)
  }

  gbarrier(cnt + CNT_OFF, 1, NBC);

  // ----- Phase 3: BN finalize from registers -----
  const float inv = 1.0f / (float)B;
  float sc[4], sh[4];
#pragma unroll
  for (int j = 0; j < 4; ++j) {
    float sum = __hip_atomic_load(wsf + STAT_OFF + j * STAT_STRIDE,
                                  __ATOMIC_RELAXED, __HIP_MEMORY_SCOPE_AGENT);
    float ssq = __hip_atomic_load(wsf + STAT_OFF + (4 + j) * STAT_STRIDE,
                                  __ATOMIC_RELAXED, __HIP_MEMORY_SCOPE_AGENT);
    float mean = sum * inv;
    float var = ssq * inv - mean * mean;
    float is = rsqrtf(var + BN_EPS_F);
    sc[j] = gamma[j] * is;
    sh[j] = beta[j] - mean * sc[j];
  }
#pragma unroll
  for (int p = 0; p < 4; ++p) {
    if (hp[p]) {
      int s = gtid + p * H;
      *(float4*)(out + (size_t)s * 4) =
          make_float4(fmaf(o[p][0], sc[0], sh[0]), fmaf(o[p][1], sc[1], sh[1]),
                      fmaf(o[p][2], sc[2], sh[2]), fmaf(o[p][3], sc[3], sh[3]));
    }
  }
}

// ===========================================================================
// Fallback path (verified plain-kernel structure).
// ===========================================================================
__global__ __launch_bounds__(256) void k_minmax_fb(const float* __restrict__ x,
                                                   unsigned* __restrict__ wsu,
                                                   int B) {
  float fmn = __builtin_inff(), fmx = -__builtin_inff();
  for (int r = blockIdx.x * blockDim.x + threadIdx.x; r < B;
       r += gridDim.x * blockDim.x) {
    float4 v = *(const float4*)(x + (size_t)r * 16);
    fmn = fminf(fmn, fminf(fminf(v.x, v.y), fminf(v.z, v.w)));
    fmx = fmaxf(fmx, fmaxf(fmaxf(v.x, v.y), fmaxf(v.z, v.w)));
  }
#pragma unroll
  for (int d = 32; d; d >>= 1) {
    fmn = fminf(fmn, __shfl_down(fmn, d));
    fmx = fmaxf(fmx, __shfl_down(fmx, d));
  }
  __shared__ float smn[4], smx[4];
  int wv = threadIdx.x >> 6, ln = threadIdx.x & 63;
  if (ln == 0) { smn[wv] = fmn; smx[wv] = fmx; }
  __syncthreads();
  if (threadIdx.x == 0) {
    atomicMin(&wsu[MINK_OFF],
              f2key(fminf(fminf(smn[0], smn[1]), fminf(smn[2], smn[3]))));
    atomicMax(&wsu[MAXK_OFF],
              f2key(fmaxf(fmaxf(smx[0], smx[1]), fmaxf(smx[2], smx[3]))));
  }
}

__global__ __launch_bounds__(256) void k_main_fb(const float* __restrict__ x,
                                                 float* wsf,
                                                 const float* __restrict__ tab,
                                                 float* __restrict__ out, int B) {
  int b = blockIdx.x * 256 + threadIdx.x;
  const unsigned* wsu = (const unsigned*)wsf;
  float mn = key2f(wsu[MINK_OFF]);
  float mx = key2f(wsu[MAXK_OFF]);
  const float ssc = TWO_PI_F * 0.5f / (mx - mn + 1e-8f);
  float o0[4] = {0, 0, 0, 0}, o1[4];
  if (b < B) {
    float4 xv = *(const float4*)(x + (size_t)b * 16);
    float a0[4] = {xv.x, xv.y, xv.z, xv.w};
    float c0[4], s0[4];
#pragma unroll
    for (int i = 0; i < 4; ++i) __sincosf((a0[i] - mn) * ssc, &s0[i], &c0[i]);
    qfc_pair(tab, c0, s0, c0, s0, o0, o1);
    *(float4*)(out + (size_t)b * 4) = make_float4(o0[0], o0[1], o0[2], o0[3]);
  }
  float vals[8] = {o0[0], o0[1], o0[2], o0[3],
                   o0[0] * o0[0], o0[1] * o0[1], o0[2] * o0[2], o0[3] * o0[3]};
#pragma unroll
  for (int j = 0; j < 8; ++j) {
#pragma unroll
    for (int d = 32; d; d >>= 1) vals[j] += __shfl_down(vals[j], d);
  }
  __shared__ float red[4][8];
  int wv = threadIdx.x >> 6, ln = threadIdx.x & 63;
  if (ln == 0) {
#pragma unroll
    for (int j = 0; j < 8; ++j) red[wv][j] = vals[j];
  }
  __syncthreads();
  if (threadIdx.x < 8) {
    float s = red[0][threadIdx.x] + red[1][threadIdx.x] + red[2][threadIdx.x] +
              red[3][threadIdx.x];
    atomicAdd(wsf + STAT_OFF + threadIdx.x * STAT_STRIDE, s);
  }
}

__global__ __launch_bounds__(256) void k_final_fb(float* __restrict__ out,
                                                  const float* __restrict__ wsf,
                                                  const float* __restrict__ gamma,
                                                  const float* __restrict__ beta,
                                                  int B) {
  int b = blockIdx.x * 256 + threadIdx.x;
  if (b >= B) return;
  float inv = 1.0f / (float)B;
  float4 v = *(float4*)(out + (size_t)b * 4);
  float vv[4] = {v.x, v.y, v.z, v.w};
  float res[4];
#pragma unroll
  for (int j = 0; j < 4; ++j) {
    float mean = wsf[STAT_OFF + j * STAT_STRIDE] * inv;
    float var = wsf[STAT_OFF + (4 + j) * STAT_STRIDE] * inv - mean * mean;
    res[j] = gamma[j] * (vv[j] - mean) * rsqrtf(var + BN_EPS_F) + beta[j];
  }
  *(float4*)(out + (size_t)b * 4) = make_float4(res[0], res[1], res[2], res[3]);
}

extern "C" void kernel_launch(void* const* d_in, const int* in_sizes, int n_in,
                              void* d_out, int out_size, void* d_ws, size_t ws_size,
                              hipStream_t stream) {
  const float* x = (const float*)d_in[0];
  const float* w = (const float*)d_in[1];
  const float* fc_w = (const float*)d_in[2];
  const float* gamma = (const float*)d_in[4];
  const float* beta = (const float*)d_in[5];
  float* out = (float*)d_out;
  float* wsf = (float*)d_ws;
  const float* tab = wsf + TAB_OFF;
  int B = in_sizes[0] / 16;

  k_init<<<1, 64, 0, stream>>>(w, fc_w, wsf);

  void* args[] = {(void*)&x,   (void*)&gamma, (void*)&beta, (void*)&wsf,
                  (void*)&tab, (void*)&out,   (void*)&B};
  hipError_t e = hipLaunchCooperativeKernel((void*)k_fused, dim3(NBC), dim3(NT),
                                            args, 0, stream);
  if (e != hipSuccess) {
    // Fallback: verified plain-kernel structure.
    k_minmax_fb<<<1024, 256, 0, stream>>>(x, (unsigned*)d_ws, B);
    k_main_fb<<<(B + 255) / 256, 256, 0, stream>>>(x, wsf, tab, out, B);
    k_final_fb<<<(B + 255) / 256, 256, 0, stream>>>(out, wsf, gamma, beta, B);
  }
}

// Round 6
// 116.265 us; speedup vs baseline: 2.5454x; 1.8924x over previous
//
#include <hip/hip_runtime.h>
#include <math.h>

#define TWO_PI_F 6.28318530717958647692f
#define BN_EPS_F 1e-5f
#define NB1 1024  // k1 blocks (scan)
#define NB2 512   // k2/k3 blocks
#define NT 256

// ---------------------------------------------------------------------------
// Workspace layout (float offsets on d_ws). All cross-kernel data is written
// with plain stores in kernel N and read in kernel N+1 (runtime handles
// inter-kernel coherence). No atomics, no zero-init required.
//   [BMIN_OFF..+1024) : per-block min   (k1 -> k2)
//   [BMAX_OFF..+1024) : per-block max   (k1 -> k2)
//   [TAB_OFF..+576)   : UrT[16][16] | UiT[16][16] | AT[16][4]  (k1 -> k2)
//   [SSLOT_OFF..+4096): per-block BN stats [blk][8] = sum0..3,ssq0..3 (k2 -> k3)
// ---------------------------------------------------------------------------
#define BMIN_OFF 256
#define BMAX_OFF 1280
#define TAB_OFF 2304
#define SSLOT_OFF 2944

// ===========================================================================
// K1: grid-stride min/max over x[:,0:4] -> per-block slots; block 0 also
// builds the fixed circuit tables (U = weight-layer unitary, A = parity@fc_w).
// ===========================================================================
__global__ __launch_bounds__(NT) void k1_scan_tab(const float* __restrict__ x,
                                                  const float* __restrict__ w,
                                                  const float* __restrict__ fc_w,
                                                  float* __restrict__ wsf, int B) {
  float fmn = __builtin_inff(), fmx = -__builtin_inff();
  for (int r = blockIdx.x * NT + threadIdx.x; r < B; r += NB1 * NT) {
    float4 v = *(const float4*)(x + (size_t)r * 16);
    fmn = fminf(fmn, fminf(fminf(v.x, v.y), fminf(v.z, v.w)));
    fmx = fmaxf(fmx, fmaxf(fmaxf(v.x, v.y), fmaxf(v.z, v.w)));
  }
#pragma unroll
  for (int d = 32; d; d >>= 1) {
    fmn = fminf(fmn, __shfl_down(fmn, d));
    fmx = fmaxf(fmx, __shfl_down(fmx, d));
  }
  __shared__ float smn[4], smx[4];
  int wv = threadIdx.x >> 6, ln = threadIdx.x & 63;
  if (ln == 0) { smn[wv] = fmn; smx[wv] = fmx; }
  __syncthreads();
  if (threadIdx.x == 0) {
    wsf[BMIN_OFF + blockIdx.x] =
        fminf(fminf(smn[0], smn[1]), fminf(smn[2], smn[3]));
    wsf[BMAX_OFF + blockIdx.x] =
        fmaxf(fmaxf(smx[0], smx[1]), fmaxf(smx[2], smx[3]));
  }

  if (blockIdx.x == 0) {
    int tid = threadIdx.x;
    if (tid < 16) {
      // Column tid of the fixed 3-layer RY/RZ/CNOT unitary; store transposed.
      float sr[16], si[16];
#pragma unroll
      for (int k = 0; k < 16; ++k) { sr[k] = (k == tid) ? 1.f : 0.f; si[k] = 0.f; }
#pragma unroll
      for (int l = 0; l < 3; ++l) {
#pragma unroll
        for (int i = 0; i < 4; ++i) {
          const int m = 8 >> i;
          float ryc, rys, rzc, rzs;
          __sincosf(0.5f * w[(l * 4 + i) * 2 + 0], &rys, &ryc);
          __sincosf(0.5f * w[(l * 4 + i) * 2 + 1], &rzs, &rzc);
#pragma unroll
          for (int k = 0; k < 16; ++k) {
            if (!(k & m)) {
              int k1 = k | m;
              float a0r = sr[k], a0i = si[k], a1r = sr[k1], a1i = si[k1];
              sr[k] = ryc * a0r - rys * a1r;
              si[k] = ryc * a0i - rys * a1i;
              sr[k1] = rys * a0r + ryc * a1r;
              si[k1] = rys * a0i + ryc * a1i;
            }
          }
#pragma unroll
          for (int k = 0; k < 16; ++k) {
            float ps = (k & m) ? rzs : -rzs;
            float r = sr[k], ii = si[k];
            sr[k] = r * rzc - ii * ps;
            si[k] = r * ps + ii * rzc;
          }
        }
#pragma unroll
        for (int c = 0; c < 4; ++c) {
          const int mc = 8 >> c;
          const int mt = 8 >> ((c + 1) & 3);
#pragma unroll
          for (int k = 0; k < 16; ++k) {
            if ((k & mc) && !(k & mt)) {
              int k2 = k | mt;
              float tt;
              tt = sr[k]; sr[k] = sr[k2]; sr[k2] = tt;
              tt = si[k]; si[k] = si[k2]; si[k2] = tt;
            }
          }
        }
      }
#pragma unroll
      for (int k = 0; k < 16; ++k) {
        wsf[TAB_OFF + tid * 16 + k] = sr[k];
        wsf[TAB_OFF + 256 + tid * 16 + k] = si[k];
      }
    } else if (tid == 16) {
      // AT[k][j] = sum_i fc_w[j][i] * Zparity(k,i)
      for (int k = 0; k < 16; ++k)
        for (int j = 0; j < 4; ++j) {
          float s = 0.f;
          for (int i = 0; i < 4; ++i)
            s += fc_w[j * 4 + i] * ((k & (8 >> i)) ? -1.f : 1.f);
          wsf[TAB_OFF + 512 + k * 4 + j] = s;
        }
    }
  }
}

// Two-sample fused circuit+linear: o = A|U v|^2 (no bias; constant bias
// cancels exactly in BatchNorm).
__device__ __forceinline__ void qfc_pair(const float* __restrict__ tab,
                                         const float* c0, const float* s0,
                                         const float* c1, const float* s1,
                                         float* o0, float* o1) {
  const float* __restrict__ Ur = tab;
  const float* __restrict__ Ui = tab + 256;
  const float* __restrict__ At = tab + 512;
  float A01_0[4] = {c0[0] * c0[1], c0[0] * s0[1], s0[0] * c0[1], s0[0] * s0[1]};
  float A23_0[4] = {c0[2] * c0[3], c0[2] * s0[3], s0[2] * c0[3], s0[2] * s0[3]};
  float A01_1[4] = {c1[0] * c1[1], c1[0] * s1[1], s1[0] * c1[1], s1[0] * s1[1]};
  float A23_1[4] = {c1[2] * c1[3], c1[2] * s1[3], s1[2] * c1[3], s1[2] * s1[3]};
  float yr0[16], yi0[16], yr1[16], yi1[16];
#pragma unroll
  for (int k = 0; k < 16; ++k) { yr0[k] = yi0[k] = yr1[k] = yi1[k] = 0.f; }
#pragma unroll
  for (int a = 0; a < 16; ++a) {
    float va0 = A01_0[a >> 2] * A23_0[a & 3];
    float va1 = A01_1[a >> 2] * A23_1[a & 3];
#pragma unroll
    for (int k = 0; k < 16; ++k) {
      float ur = Ur[a * 16 + k], ui = Ui[a * 16 + k];
      yr0[k] = fmaf(ur, va0, yr0[k]);
      yi0[k] = fmaf(ui, va0, yi0[k]);
      yr1[k] = fmaf(ur, va1, yr1[k]);
      yi1[k] = fmaf(ui, va1, yi1[k]);
    }
  }
#pragma unroll
  for (int j = 0; j < 4; ++j) { o0[j] = 0.f; o1[j] = 0.f; }
#pragma unroll
  for (int k = 0; k < 16; ++k) {
    float p0 = fmaf(yr0[k], yr0[k], yi0[k] * yi0[k]);
    float p1 = fmaf(yr1[k], yr1[k], yi1[k] * yi1[k]);
#pragma unroll
    for (int j = 0; j < 4; ++j) {
      float av = At[k * 4 + j];
      o0[j] = fmaf(av, p0, o0[j]);
      o1[j] = fmaf(av, p1, o1[j]);
    }
  }
}

// ===========================================================================
// K2: reduce min/max slots per-wave; 4 samples/thread circuit+linear; write
// pre-BN out; per-block BN stat partials -> plain-store slots [blk][8].
// ===========================================================================
__global__ __launch_bounds__(NT) void k2_main(const float* __restrict__ x,
                                              const float* __restrict__ wsf,
                                              float* __restrict__ sslot,
                                              float* __restrict__ out, int B) {
  const int tid = threadIdx.x;
  const int gtid = blockIdx.x * NT + tid;
  const int H = NB2 * NT;  // 131072
  const int wv = tid >> 6, ln = tid & 63;
  const float* __restrict__ tab = wsf + TAB_OFF;

  // global min/max from the 1024 k1 slots (redundant per-wave reduce)
  float gm = __builtin_inff(), gM = -__builtin_inff();
#pragma unroll
  for (int q = 0; q < NB1 / 64; ++q) {
    int i = ln + q * 64;
    gm = fminf(gm, wsf[BMIN_OFF + i]);
    gM = fmaxf(gM, wsf[BMAX_OFF + i]);
  }
#pragma unroll
  for (int d = 32; d; d >>= 1) {
    gm = fminf(gm, __shfl_down(gm, d));
    gM = fmaxf(gM, __shfl_down(gM, d));
  }
  gm = __shfl(gm, 0);
  gM = __shfl(gM, 0);
  const float ssc = TWO_PI_F * 0.5f / (gM - gm + 1e-8f);  // half-angle scale

  float4 xs[4];
  bool hp[4];
#pragma unroll
  for (int p = 0; p < 4; ++p) {
    int s = gtid + p * H;
    hp[p] = s < B;
    xs[p] = hp[p] ? *(const float4*)(x + (size_t)s * 16) : make_float4(0, 0, 0, 0);
  }

  float o[4][4];
#pragma unroll
  for (int pp = 0; pp < 2; ++pp) {
    const float4 xa = xs[pp * 2], xb = xs[pp * 2 + 1];
    float a0[4] = {xa.x, xa.y, xa.z, xa.w};
    float a1[4] = {xb.x, xb.y, xb.z, xb.w};
    float c0[4], s0[4], c1[4], s1[4];
#pragma unroll
    for (int i = 0; i < 4; ++i) {
      __sincosf((a0[i] - gm) * ssc, &s0[i], &c0[i]);
      __sincosf((a1[i] - gm) * ssc, &s1[i], &c1[i]);
    }
    qfc_pair(tab, c0, s0, c1, s1, o[pp * 2], o[pp * 2 + 1]);
  }

#pragma unroll
  for (int p = 0; p < 4; ++p) {
    if (hp[p]) {
      int s = gtid + p * H;
      *(float4*)(out + (size_t)s * 4) =
          make_float4(o[p][0], o[p][1], o[p][2], o[p][3]);
    }
  }

  // per-block BN stat partials
  float vals[8];
#pragma unroll
  for (int j = 0; j < 4; ++j) {
    float s = 0.f, ss = 0.f;
#pragma unroll
    for (int p = 0; p < 4; ++p) {
      float v = hp[p] ? o[p][j] : 0.f;
      s += v;
      ss = fmaf(v, v, ss);
    }
    vals[j] = s;
    vals[4 + j] = ss;
  }
#pragma unroll
  for (int j = 0; j < 8; ++j) {
#pragma unroll
    for (int d = 32; d; d >>= 1) vals[j] += __shfl_down(vals[j], d);
  }
  __shared__ float red[4][8];
  if (ln == 0) {
#pragma unroll
    for (int j = 0; j < 8; ++j) red[wv][j] = vals[j];
  }
  __syncthreads();
  if (tid < 8) {
    sslot[blockIdx.x * 8 + tid] =
        red[0][tid] + red[1][tid] + red[2][tid] + red[3][tid];
  }
}

// ===========================================================================
// K3: per-wave reduce of the 512x8 stat slots (coalesced 64-float rows),
// then BN finalize in-place on out.
// ===========================================================================
__global__ __launch_bounds__(NT) void k3_final(float* __restrict__ out,
                                               const float* __restrict__ sslot,
                                               const float* __restrict__ gamma,
                                               const float* __restrict__ beta,
                                               int B) {
  const int tid = threadIdx.x;
  const int gtid = blockIdx.x * NT + tid;
  const int H = NB2 * NT;
  const int ln = tid & 63;

  // flat element e = blk*8 + j; lane ln sums e ≡ ln (mod 64) -> j = ln&7
  float v = 0.f;
#pragma unroll
  for (int k = 0; k < (NB2 * 8) / 64; ++k) v += sslot[k * 64 + ln];
#pragma unroll
  for (int d = 32; d >= 8; d >>= 1) v += __shfl_down(v, d);
  // lanes 0..7 hold totals for j=0..7; broadcast all 8 to every lane
  float st[8];
#pragma unroll
  for (int j = 0; j < 8; ++j) st[j] = __shfl(v, j);

  const float inv = 1.0f / (float)B;
  float sc[4], sh[4];
#pragma unroll
  for (int j = 0; j < 4; ++j) {
    float mean = st[j] * inv;
    float var = st[4 + j] * inv - mean * mean;
    float is = rsqrtf(var + BN_EPS_F);
    sc[j] = gamma[j] * is;
    sh[j] = beta[j] - mean * sc[j];
  }
#pragma unroll
  for (int p = 0; p < 4; ++p) {
    int s = gtid + p * H;
    if (s < B) {
      float4 q = *(float4*)(out + (size_t)s * 4);
      *(float4*)(out + (size_t)s * 4) =
          make_float4(fmaf(q.x, sc[0], sh[0]), fmaf(q.y, sc[1], sh[1]),
                      fmaf(q.z, sc[2], sh[2]), fmaf(q.w, sc[3], sh[3]));
    }
  }
}

extern "C" void kernel_launch(void* const* d_in, const int* in_sizes, int n_in,
                              void* d_out, int out_size, void* d_ws, size_t ws_size,
                              hipStream_t stream) {
  const float* x = (const float*)d_in[0];
  const float* w = (const float*)d_in[1];
  const float* fc_w = (const float*)d_in[2];
  const float* gamma = (const float*)d_in[4];
  const float* beta = (const float*)d_in[5];
  float* out = (float*)d_out;
  float* wsf = (float*)d_ws;
  int B = in_sizes[0] / 16;

  k1_scan_tab<<<NB1, NT, 0, stream>>>(x, w, fc_w, wsf, B);
  k2_main<<<NB2, NT, 0, stream>>>(x, wsf, wsf + SSLOT_OFF, out, B);
  k3_final<<<NB2, NT, 0, stream>>>(out, wsf + SSLOT_OFF, gamma, beta, B);
}

// Round 7
// 111.290 us; speedup vs baseline: 2.6592x; 1.0447x over previous
//
#include <hip/hip_runtime.h>
#include <math.h>

#define TWO_PI_F 6.28318530717958647692f
#define BN_EPS_F 1e-5f
#define NB1 2048  // k1 blocks (scan): 1 row/thread exactly at B=524288
#define NB2 1024  // k2/k3 blocks
#define NT 256

// ---------------------------------------------------------------------------
// Workspace layout (float offsets on d_ws). All cross-kernel data is written
// with plain stores in kernel N and read in kernel N+1 (runtime handles
// inter-kernel coherence). No atomics, no zero-init required.
//   [BMIN_OFF..+2048) : per-block min   (k1 -> k2)
//   [BMAX_OFF..+2048) : per-block max   (k1 -> k2)
//   [TAB_OFF..+576)   : UrT[16][16] | UiT[16][16] | AT[16][4]  (k1 -> k2)
//   [SSLOT_OFF..+8192): per-block BN stats [blk][8] = sum0..3,ssq0..3 (k2 -> k3)
// ---------------------------------------------------------------------------
#define BMIN_OFF 256
#define BMAX_OFF 2304
#define TAB_OFF 4352
#define SSLOT_OFF 4992

// ===========================================================================
// K1: min/max over x[:,0:4], 1 row/thread -> per-block slots; block 0 also
// builds the fixed circuit tables (U = weight-layer unitary, A = parity@fc_w).
// ===========================================================================
__global__ __launch_bounds__(NT) void k1_scan_tab(const float* __restrict__ x,
                                                  const float* __restrict__ w,
                                                  const float* __restrict__ fc_w,
                                                  float* __restrict__ wsf, int B) {
  int r = blockIdx.x * NT + threadIdx.x;
  float fmn = __builtin_inff(), fmx = -__builtin_inff();
  if (r < B) {
    float4 v = *(const float4*)(x + (size_t)r * 16);
    fmn = fminf(fminf(v.x, v.y), fminf(v.z, v.w));
    fmx = fmaxf(fmaxf(v.x, v.y), fmaxf(v.z, v.w));
  }
#pragma unroll
  for (int d = 32; d; d >>= 1) {
    fmn = fminf(fmn, __shfl_down(fmn, d));
    fmx = fmaxf(fmx, __shfl_down(fmx, d));
  }
  __shared__ float smn[4], smx[4];
  int wv = threadIdx.x >> 6, ln = threadIdx.x & 63;
  if (ln == 0) { smn[wv] = fmn; smx[wv] = fmx; }
  __syncthreads();
  if (threadIdx.x == 0) {
    wsf[BMIN_OFF + blockIdx.x] =
        fminf(fminf(smn[0], smn[1]), fminf(smn[2], smn[3]));
    wsf[BMAX_OFF + blockIdx.x] =
        fmaxf(fmaxf(smx[0], smx[1]), fmaxf(smx[2], smx[3]));
  }

  if (blockIdx.x == 0) {
    int tid = threadIdx.x;
    if (tid < 16) {
      // Column tid of the fixed 3-layer RY/RZ/CNOT unitary; store transposed.
      float sr[16], si[16];
#pragma unroll
      for (int k = 0; k < 16; ++k) { sr[k] = (k == tid) ? 1.f : 0.f; si[k] = 0.f; }
#pragma unroll
      for (int l = 0; l < 3; ++l) {
#pragma unroll
        for (int i = 0; i < 4; ++i) {
          const int m = 8 >> i;
          float ryc, rys, rzc, rzs;
          __sincosf(0.5f * w[(l * 4 + i) * 2 + 0], &rys, &ryc);
          __sincosf(0.5f * w[(l * 4 + i) * 2 + 1], &rzs, &rzc);
#pragma unroll
          for (int k = 0; k < 16; ++k) {
            if (!(k & m)) {
              int k1 = k | m;
              float a0r = sr[k], a0i = si[k], a1r = sr[k1], a1i = si[k1];
              sr[k] = ryc * a0r - rys * a1r;
              si[k] = ryc * a0i - rys * a1i;
              sr[k1] = rys * a0r + ryc * a1r;
              si[k1] = rys * a0i + ryc * a1i;
            }
          }
#pragma unroll
          for (int k = 0; k < 16; ++k) {
            float ps = (k & m) ? rzs : -rzs;
            float rr = sr[k], ii = si[k];
            sr[k] = rr * rzc - ii * ps;
            si[k] = rr * ps + ii * rzc;
          }
        }
#pragma unroll
        for (int c = 0; c < 4; ++c) {
          const int mc = 8 >> c;
          const int mt = 8 >> ((c + 1) & 3);
#pragma unroll
          for (int k = 0; k < 16; ++k) {
            if ((k & mc) && !(k & mt)) {
              int k2 = k | mt;
              float tt;
              tt = sr[k]; sr[k] = sr[k2]; sr[k2] = tt;
              tt = si[k]; si[k] = si[k2]; si[k2] = tt;
            }
          }
        }
      }
#pragma unroll
      for (int k = 0; k < 16; ++k) {
        wsf[TAB_OFF + tid * 16 + k] = sr[k];
        wsf[TAB_OFF + 256 + tid * 16 + k] = si[k];
      }
    } else if (tid == 16) {
      // AT[k][j] = sum_i fc_w[j][i] * Zparity(k,i)
      for (int k = 0; k < 16; ++k)
        for (int j = 0; j < 4; ++j) {
          float s = 0.f;
          for (int i = 0; i < 4; ++i)
            s += fc_w[j * 4 + i] * ((k & (8 >> i)) ? -1.f : 1.f);
          wsf[TAB_OFF + 512 + k * 4 + j] = s;
        }
    }
  }
}

// Two-sample fused circuit+linear: o = A|U v|^2 (no bias; constant bias
// cancels exactly in BatchNorm). tab -> wave-uniform scalar loads.
__device__ __forceinline__ void qfc_pair(const float* __restrict__ tab,
                                         const float* c0, const float* s0,
                                         const float* c1, const float* s1,
                                         float* o0, float* o1) {
  const float* __restrict__ Ur = tab;
  const float* __restrict__ Ui = tab + 256;
  const float* __restrict__ At = tab + 512;
  float A01_0[4] = {c0[0] * c0[1], c0[0] * s0[1], s0[0] * c0[1], s0[0] * s0[1]};
  float A23_0[4] = {c0[2] * c0[3], c0[2] * s0[3], s0[2] * c0[3], s0[2] * s0[3]};
  float A01_1[4] = {c1[0] * c1[1], c1[0] * s1[1], s1[0] * c1[1], s1[0] * s1[1]};
  float A23_1[4] = {c1[2] * c1[3], c1[2] * s1[3], s1[2] * c1[3], s1[2] * s1[3]};
  float yr0[16], yi0[16], yr1[16], yi1[16];
#pragma unroll
  for (int k = 0; k < 16; ++k) { yr0[k] = yi0[k] = yr1[k] = yi1[k] = 0.f; }
#pragma unroll
  for (int a = 0; a < 16; ++a) {
    float va0 = A01_0[a >> 2] * A23_0[a & 3];
    float va1 = A01_1[a >> 2] * A23_1[a & 3];
#pragma unroll
    for (int k = 0; k < 16; ++k) {
      float ur = Ur[a * 16 + k], ui = Ui[a * 16 + k];
      yr0[k] = fmaf(ur, va0, yr0[k]);
      yi0[k] = fmaf(ui, va0, yi0[k]);
      yr1[k] = fmaf(ur, va1, yr1[k]);
      yi1[k] = fmaf(ui, va1, yi1[k]);
    }
  }
#pragma unroll
  for (int j = 0; j < 4; ++j) { o0[j] = 0.f; o1[j] = 0.f; }
#pragma unroll
  for (int k = 0; k < 16; ++k) {
    float p0 = fmaf(yr0[k], yr0[k], yi0[k] * yi0[k]);
    float p1 = fmaf(yr1[k], yr1[k], yi1[k] * yi1[k]);
#pragma unroll
    for (int j = 0; j < 4; ++j) {
      float av = At[k * 4 + j];
      o0[j] = fmaf(av, p0, o0[j]);
      o1[j] = fmaf(av, p1, o1[j]);
    }
  }
}

// ===========================================================================
// K2: reduce min/max slots per-wave; 2 samples/thread circuit+linear; write
// pre-BN out; per-block BN stat partials -> plain-store slots [blk][8].
// ===========================================================================
__global__ __launch_bounds__(NT) void k2_main(const float* __restrict__ x,
                                              const float* __restrict__ wsf,
                                              float* __restrict__ sslot,
                                              float* __restrict__ out, int B) {
  const int tid = threadIdx.x;
  const int gtid = blockIdx.x * NT + tid;
  const int H = NB2 * NT;  // 262144
  const int wv = tid >> 6, ln = tid & 63;
  const float* __restrict__ tab = wsf + TAB_OFF;

  // global min/max from the 2048 k1 slots (redundant per-wave reduce)
  float gm = __builtin_inff(), gM = -__builtin_inff();
#pragma unroll
  for (int q = 0; q < NB1 / 64; ++q) {
    int i = ln + q * 64;
    gm = fminf(gm, wsf[BMIN_OFF + i]);
    gM = fmaxf(gM, wsf[BMAX_OFF + i]);
  }
#pragma unroll
  for (int d = 32; d; d >>= 1) {
    gm = fminf(gm, __shfl_down(gm, d));
    gM = fmaxf(gM, __shfl_down(gM, d));
  }
  gm = __shfl(gm, 0);
  gM = __shfl(gM, 0);
  const float ssc = TWO_PI_F * 0.5f / (gM - gm + 1e-8f);  // half-angle scale

  const int s0 = gtid, s1 = gtid + H;
  const bool h0 = s0 < B, h1 = s1 < B;
  float4 xa = h0 ? *(const float4*)(x + (size_t)s0 * 16) : make_float4(0, 0, 0, 0);
  float4 xb = h1 ? *(const float4*)(x + (size_t)s1 * 16) : make_float4(0, 0, 0, 0);

  float a0[4] = {xa.x, xa.y, xa.z, xa.w};
  float a1[4] = {xb.x, xb.y, xb.z, xb.w};
  float c0[4], sn0[4], c1[4], sn1[4];
#pragma unroll
  for (int i = 0; i < 4; ++i) {
    __sincosf((a0[i] - gm) * ssc, &sn0[i], &c0[i]);
    __sincosf((a1[i] - gm) * ssc, &sn1[i], &c1[i]);
  }
  float o0[4], o1[4];
  qfc_pair(tab, c0, sn0, c1, sn1, o0, o1);

  if (h0)
    *(float4*)(out + (size_t)s0 * 4) = make_float4(o0[0], o0[1], o0[2], o0[3]);
  if (h1)
    *(float4*)(out + (size_t)s1 * 4) = make_float4(o1[0], o1[1], o1[2], o1[3]);

  // per-block BN stat partials
  float vals[8];
#pragma unroll
  for (int j = 0; j < 4; ++j) {
    float v0 = h0 ? o0[j] : 0.f, v1 = h1 ? o1[j] : 0.f;
    vals[j] = v0 + v1;
    vals[4 + j] = fmaf(v0, v0, v1 * v1);
  }
#pragma unroll
  for (int j = 0; j < 8; ++j) {
#pragma unroll
    for (int d = 32; d; d >>= 1) vals[j] += __shfl_down(vals[j], d);
  }
  __shared__ float red[4][8];
  if (ln == 0) {
#pragma unroll
    for (int j = 0; j < 8; ++j) red[wv][j] = vals[j];
  }
  __syncthreads();
  if (tid < 8) {
    sslot[blockIdx.x * 8 + tid] =
        red[0][tid] + red[1][tid] + red[2][tid] + red[3][tid];
  }
}

// ===========================================================================
// K3: per-wave reduce of the 1024x8 stat slots (coalesced 64-float rows),
// then BN finalize in-place on out (2 float4s/thread).
// ===========================================================================
__global__ __launch_bounds__(NT) void k3_final(float* __restrict__ out,
                                               const float* __restrict__ sslot,
                                               const float* __restrict__ gamma,
                                               const float* __restrict__ beta,
                                               int B) {
  const int tid = threadIdx.x;
  const int gtid = blockIdx.x * NT + tid;
  const int H = NB2 * NT;
  const int ln = tid & 63;

  // flat element e = blk*8 + j; lane ln sums e ≡ ln (mod 64) -> j = ln&7
  float v = 0.f;
#pragma unroll
  for (int k = 0; k < (NB2 * 8) / 64; ++k) v += sslot[k * 64 + ln];
#pragma unroll
  for (int d = 32; d >= 8; d >>= 1) v += __shfl_down(v, d);
  // lanes 0..7 hold totals for j=0..7; broadcast all 8 to every lane
  float st[8];
#pragma unroll
  for (int j = 0; j < 8; ++j) st[j] = __shfl(v, j);

  const float inv = 1.0f / (float)B;
  float sc[4], sh[4];
#pragma unroll
  for (int j = 0; j < 4; ++j) {
    float mean = st[j] * inv;
    float var = st[4 + j] * inv - mean * mean;
    float is = rsqrtf(var + BN_EPS_F);
    sc[j] = gamma[j] * is;
    sh[j] = beta[j] - mean * sc[j];
  }
#pragma unroll
  for (int p = 0; p < 2; ++p) {
    int s = gtid + p * H;
    if (s < B) {
      float4 q = *(float4*)(out + (size_t)s * 4);
      *(float4*)(out + (size_t)s * 4) =
          make_float4(fmaf(q.x, sc[0], sh[0]), fmaf(q.y, sc[1], sh[1]),
                      fmaf(q.z, sc[2], sh[2]), fmaf(q.w, sc[3], sh[3]));
    }
  }
}

extern "C" void kernel_launch(void* const* d_in, const int* in_sizes, int n_in,
                              void* d_out, int out_size, void* d_ws, size_t ws_size,
                              hipStream_t stream) {
  const float* x = (const float*)d_in[0];
  const float* w = (const float*)d_in[1];
  const float* fc_w = (const float*)d_in[2];
  const float* gamma = (const float*)d_in[4];
  const float* beta = (const float*)d_in[5];
  float* out = (float*)d_out;
  float* wsf = (float*)d_ws;
  int B = in_sizes[0] / 16;

  k1_scan_tab<<<NB1, NT, 0, stream>>>(x, w, fc_w, wsf, B);
  k2_main<<<NB2, NT, 0, stream>>>(x, wsf, wsf + SSLOT_OFF, out, B);
  k3_final<<<NB2, NT, 0, stream>>>(out, wsf + SSLOT_OFF, gamma, beta, B);
}